// Round 11
// baseline (219.766 us; speedup 1.0000x reference)
//
#include <hip/hip_runtime.h>

// Problem constants (match reference)
constexpr int B    = 64;
constexpr int E    = 512;
constexpr int P    = 31;    // patch size
constexpr int S    = 200;   // canvas size
constexpr int HALF = 15;

// Banding: each block owns (batch, 50-row band); canvas band lives in LDS
constexpr int BAND    = 50;
constexpr int NBANDS  = S / BAND;        // 4
constexpr int THREADS = 1024;            // 16 waves
constexpr int NW      = THREADS / 64;    // 16
constexpr int EPW     = E / NW;          // 32 emitters per wave
constexpr int CANV    = BAND * S;        // 10000 floats = 40 KB

__global__ __launch_bounds__(THREADS, 8)   // 8 waves/SIMD -> 2 blocks/CU, VGPR <= 64
void imgs4dto3d_band_kernel(const float* __restrict__ img,
                            const int*   __restrict__ xyz,
                            float*       __restrict__ out)
{
    __shared__ __align__(16) float canvas[CANV];   // 40 KB
    __shared__ unsigned xy[E];                     // 2 KB packed (x | y<<8)

    const int band = blockIdx.x;
    const int b    = blockIdx.y;
    const int r0   = band * BAND;
    const int tid  = threadIdx.x;
    const int wid  = tid >> 6;
    const int lane = tid & 63;

    // ---- stage all emitters' (x,y) into LDS, packed ----
    if (tid < E) {
        const int* p = xyz + (size_t)(b * E + tid) * 3;
        xy[tid] = (unsigned)p[0] | ((unsigned)p[1] << 8);   // x<=184<256, y<=184<256
    }
    // ---- zero the band ----
    {
        float4* c4 = reinterpret_cast<float4*>(canvas);
        for (int i = tid; i < CANV / 4; i += THREADS)
            c4[i] = make_float4(0.f, 0.f, 0.f, 0.f);
    }
    __syncthreads();

    // lane map: half = row parity (2 rows/iteration), col = 0..31 (31 active)
    const int  half  = lane >> 5;
    const int  col   = lane & 31;
    const bool colok = (col < P);

    // ---- scatter: each wave owns 32 whole emitters; LDS-broadcast metadata ----
    const int ebase = wid * EPW;
    unsigned cur = xy[ebase];
    for (int k = 0; k < EPW; ++k) {
        const unsigned nxt = (k + 1 < EPW) ? xy[ebase + k + 1] : cur;  // prefetch
        const int e = ebase + k;
        const int x = (int)(cur & 255u);
        const int y = (int)(cur >> 8);
        cur = nxt;

        // intersect patch rows [x-15, x+16) with band rows [r0, r0+BAND)
        const int r_lo = max(x - HALF, r0);
        const int r_hi = min(x + HALF + 1, r0 + BAND);
        if (r_lo >= r_hi) continue;                  // wave-uniform branch

        const int i_lo = r_lo - (x - HALF);          // patch-row range in band
        const int i_hi = r_hi - (x - HALF);

        const float* src = img + (size_t)(b * E + e) * (P * P) + half * P + col;
        float*       dst = canvas + (x - HALF - r0 + half) * S + (y - HALF + col);

        // stage 1: all predicated loads issued (16 in flight)
        float v[16];
        #pragma unroll
        for (int it = 0; it < 16; ++it) {
            const int  row = 2 * it + half;          // patch row 0..31
            const bool act = colok && (row >= i_lo) && (row < i_hi);
            v[it] = act ? src[62 * it] : 0.f;        // img[e][row][col], contiguous
        }
        // stage 2: LDS atomics
        #pragma unroll
        for (int it = 0; it < 16; ++it) {
            const int  row = 2 * it + half;
            const bool act = colok && (row >= i_lo) && (row < i_hi);
            if (act) atomicAdd(dst + 2 * it * S, v[it]);
        }
    }
    __syncthreads();

    // ---- dump: plain coalesced float4 stores; each out pixel written exactly once ----
    {
        const float4* c4 = reinterpret_cast<const float4*>(canvas);
        float4* ov = reinterpret_cast<float4*>(out + (size_t)b * (S * S) + (size_t)r0 * S);
        for (int i = tid; i < CANV / 4; i += THREADS)
            ov[i] = c4[i];
    }
}

extern "C" void kernel_launch(void* const* d_in, const int* in_sizes, int n_in,
                              void* d_out, int out_size, void* d_ws, size_t ws_size,
                              hipStream_t stream)
{
    const float* img = (const float*)d_in[0];   // [B, E, P, P] fp32
    const int*   xyz = (const int*)d_in[1];     // [B, E, 3] int32
    float*       out = (float*)d_out;           // [B, 1, S, S] fp32

    dim3 grid(NBANDS, B);                        // 256 blocks
    imgs4dto3d_band_kernel<<<grid, THREADS, 0, stream>>>(img, xyz, out);
}

// Round 12
// 94.210 us; speedup vs baseline: 2.3327x; 2.3327x over previous
//
#include <hip/hip_runtime.h>

// Problem constants (match reference)
constexpr int B    = 64;
constexpr int E    = 512;
constexpr int P    = 31;    // patch size
constexpr int S    = 200;   // canvas size
constexpr int HALF = 15;

// Tiling
constexpr int TS     = 16;
constexpr int NTD    = (S + TS - 1) / TS;    // 13 tiles per dim
constexpr int NTILES = NTD * NTD;            // 169 tiles per batch
constexpr int NBINS  = B * NTILES;           // 10816
constexpr int CAP    = 128;                  // bin capacity (mean ~27, max ~65)

// Gather launch: one BLOCK per tile; its 4 waves split the bin
constexpr int THREADS = 256;
constexpr int NW      = THREADS / 64;        // 4 waves

__global__ __launch_bounds__(512)
void imgs4dto3d_bin_kernel(const int* __restrict__ xyz,
                           int*       __restrict__ counts,
                           unsigned*  __restrict__ entries)
{
    const int b = blockIdx.x;
    const int e = threadIdx.x;
    const int x = xyz[(size_t)(b * E + e) * 3 + 0];
    const int y = xyz[(size_t)(b * E + e) * 3 + 1];
    const unsigned pk = (unsigned)e | ((unsigned)x << 9) | ((unsigned)y << 17);

    const int tr_lo = (x - HALF) >> 4, tr_hi = (x + HALF) >> 4;
    const int tc_lo = (y - HALF) >> 4, tc_hi = (y + HALF) >> 4;

    for (int tr = tr_lo; tr <= tr_hi; ++tr) {
        for (int tc = tc_lo; tc <= tc_hi; ++tc) {
            const int bin = b * NTILES + tr * NTD + tc;
            const int pos = atomicAdd(&counts[bin], 1);
            if (pos < CAP) entries[(size_t)bin * CAP + pos] = pk;
        }
    }
}

__global__ __launch_bounds__(THREADS, 8)
void imgs4dto3d_gather_kernel(const float*    __restrict__ img,
                              const int*      __restrict__ counts,
                              const unsigned* __restrict__ entries,
                              float*          __restrict__ out)
{
    const int b    = blockIdx.y;
    const int t    = blockIdx.x;            // tile index, 0..NTILES-1
    const int tid  = threadIdx.x;
    const int wid  = tid >> 6;
    const int lane = tid & 63;

    const int tr = t / NTD;
    const int tc = t % NTD;
    const int r0 = tr * TS;
    const int c0 = tc * TS;

    // lane map (round-6 verified): col = lane&15, rowg = lane>>4; 4 rows per lane
    const int col  = lane & 15;
    const int rowg = lane >> 4;
    const int c    = c0 + col;

    const int rr = r0 + rowg * 4 + HALF;    // pr0 = rr - x
    const int cc = c + HALF;                // pc  = cc - y

    // this block's bin, split into 4-aligned contiguous chunks across the 4 waves
    const int bin = b * NTILES + t;
    const int n   = min(counts[bin], CAP);
    const int qsz = ((n + NW * 4 - 1) / (NW * 4)) * 4;   // per-wave chunk, multiple of 4
    const int lo  = min(n, wid * qsz);
    const int hi  = min(n, lo + qsz);

    const uint4* lst = reinterpret_cast<const uint4*>(entries + (size_t)bin * CAP);

    float a0 = 0.f, a1 = 0.f, a2 = 0.f, a3 = 0.f;
    const float* imgb = img + (size_t)b * E * (P * P);

    uint4 cur = (lo < hi) ? lst[lo >> 2] : make_uint4(0u, 0u, 0u, 0u);
    for (int i = lo; i < hi; i += 4) {
        const uint4 nxt = (i + 4 < hi) ? lst[(i >> 2) + 1] : cur;   // prefetch
        const unsigned pks[4] = {cur.x, cur.y, cur.z, cur.w};
        #pragma unroll
        for (int u = 0; u < 4; ++u) {
            const bool inb = (i + u) < hi;           // wave-uniform
            const unsigned pk = pks[u];
            const int e = (int)(pk & 511u);
            const int x = (int)((pk >> 9) & 255u);
            const int y = (int)(pk >> 17);

            const int pc  = cc - y;                  // patch col (verified math)
            const int pr0 = rr - x;                  // patch row for q=0
            const bool colok = inb && ((unsigned)pc <= 30u);
            const size_t base = (size_t)e * (P * P);
            const bool k0 = colok && ((unsigned)(pr0 + 0) <= 30u);
            const bool k1 = colok && ((unsigned)(pr0 + 1) <= 30u);
            const bool k2 = colok && ((unsigned)(pr0 + 2) <= 30u);
            const bool k3 = colok && ((unsigned)(pr0 + 3) <= 30u);
            a0 += k0 ? imgb[base + (pr0 + 0) * P + pc] : 0.f;
            a1 += k1 ? imgb[base + (pr0 + 1) * P + pc] : 0.f;
            a2 += k2 ? imgb[base + (pr0 + 2) * P + pc] : 0.f;
            a3 += k3 ? imgb[base + (pr0 + 3) * P + pc] : 0.f;
        }
        cur = nxt;
    }

    // ---- reduce the 4 waves' partials in LDS (all accesses lane-consecutive) ----
    __shared__ float part[NW * THREADS];    // 4 KB
    part[wid * THREADS + 0 * 64 + lane] = a0;
    part[wid * THREADS + 1 * 64 + lane] = a1;
    part[wid * THREADS + 2 * 64 + lane] = a2;
    part[wid * THREADS + 3 * 64 + lane] = a3;
    __syncthreads();

    // thread tid owns pixel p=tid: q = tid>>6, lane' = tid&63
    const int q     = tid >> 6;
    const int lane2 = tid & 63;
    const int row   = r0 + ((lane2 >> 4) << 2) + q;
    const int cst   = c0 + (lane2 & 15);
    const float v = part[0 * THREADS + tid] + part[1 * THREADS + tid] +
                    part[2 * THREADS + tid] + part[3 * THREADS + tid];
    if (row < S && cst < S) {
        out[(size_t)b * (S * S) + row * S + cst] = v;
    }
}

extern "C" void kernel_launch(void* const* d_in, const int* in_sizes, int n_in,
                              void* d_out, int out_size, void* d_ws, size_t ws_size,
                              hipStream_t stream)
{
    const float* img = (const float*)d_in[0];   // [B, E, P, P] fp32
    const int*   xyz = (const int*)d_in[1];     // [B, E, 3] int32
    float*       out = (float*)d_out;           // [B, 1, S, S] fp32

    int*      counts  = (int*)d_ws;
    unsigned* entries = (unsigned*)d_ws + NBINS;

    hipMemsetAsync(counts, 0, (size_t)NBINS * sizeof(int), stream);

    imgs4dto3d_bin_kernel<<<B, E, 0, stream>>>(xyz, counts, entries);

    dim3 grid(NTILES, B);                        // one block per (tile, batch)
    imgs4dto3d_gather_kernel<<<grid, THREADS, 0, stream>>>(img, counts, entries, out);
}

// Round 13
// 82.537 us; speedup vs baseline: 2.6626x; 1.1414x over previous
//
#include <hip/hip_runtime.h>

// Problem constants (match reference)
constexpr int B    = 64;
constexpr int E    = 512;
constexpr int P    = 31;    // patch size
constexpr int S    = 200;   // canvas size
constexpr int HALF = 15;

// Tiling: 32x32 canvas tiles
constexpr int TS     = 32;
constexpr int NTD    = (S + TS - 1) / TS;    // 7 tiles per dim
constexpr int NTILES = NTD * NTD;            // 49 tiles per batch
constexpr int NBINS  = B * NTILES;           // 3136
constexpr int CAP    = 128;                  // bin capacity (mean ~39, tail ~75)

constexpr int THREADS = 256;                 // one block per tile; 4 px per thread

__global__ __launch_bounds__(512)
void imgs4dto3d_bin_kernel(const int* __restrict__ xyz,
                           int*       __restrict__ counts,
                           unsigned*  __restrict__ entries)
{
    const int b = blockIdx.x;
    const int e = threadIdx.x;
    const int x = xyz[(size_t)(b * E + e) * 3 + 0];
    const int y = xyz[(size_t)(b * E + e) * 3 + 1];
    const unsigned pk = (unsigned)e | ((unsigned)x << 9) | ((unsigned)y << 17);

    const int tr_lo = (x - HALF) >> 5, tr_hi = (x + HALF) >> 5;   // at most 2 per dim
    const int tc_lo = (y - HALF) >> 5, tc_hi = (y + HALF) >> 5;

    for (int tr = tr_lo; tr <= tr_hi; ++tr) {
        for (int tc = tc_lo; tc <= tc_hi; ++tc) {
            const int bin = b * NTILES + tr * NTD + tc;
            const int pos = atomicAdd(&counts[bin], 1);
            if (pos < CAP) entries[(size_t)bin * CAP + pos] = pk;
        }
    }
}

__global__ __launch_bounds__(THREADS, 8)
void imgs4dto3d_gather_kernel(const float*    __restrict__ img,
                              const int*      __restrict__ counts,
                              const unsigned* __restrict__ entries,
                              float*          __restrict__ out)
{
    const int b   = blockIdx.y;
    const int t   = blockIdx.x;             // tile index, 0..NTILES-1
    const int tid = threadIdx.x;

    const int tr = t / NTD;
    const int tc = t % NTD;
    const int r0 = tr * TS;
    const int c0 = tc * TS;

    // thread owns 4 rows of one column: col = tid&31 (coalesced), rowg = tid>>5
    const int col  = tid & 31;
    const int rowg = tid >> 5;              // 0..7
    const int c    = c0 + col;

    const int rr = r0 + rowg * 4 + HALF;    // pr0 = rr - x  (verified R6/R12 math)
    const int cc = c + HALF;                // pc  = cc - y

    const int bin = b * NTILES + t;
    const int n   = min(counts[bin], CAP);
    const uint4* lst = reinterpret_cast<const uint4*>(entries + (size_t)bin * CAP);

    float a0 = 0.f, a1 = 0.f, a2 = 0.f, a3 = 0.f;
    const float* imgb = img + (size_t)b * E * (P * P);

    const int niter = (n + 3) >> 2;
    uint4 cur = (niter > 0) ? lst[0] : make_uint4(0u, 0u, 0u, 0u);
    for (int i = 0; i < niter; ++i) {
        const uint4 nxt = (i + 1 < niter) ? lst[i + 1] : cur;   // prefetch next 4 entries
        const unsigned pks[4] = {cur.x, cur.y, cur.z, cur.w};
        #pragma unroll
        for (int u = 0; u < 4; ++u) {
            const bool inb = (4 * i + u) < n;            // wave-uniform
            const unsigned pk = pks[u];
            const int e = (int)(pk & 511u);
            const int x = (int)((pk >> 9) & 255u);
            const int y = (int)(pk >> 17);

            const int pc  = cc - y;                      // patch col (fixed per lane)
            const int pr0 = rr - x;                      // patch row for q=0
            const bool colok = inb && ((unsigned)pc <= 30u);
            const size_t base = (size_t)e * (P * P);
            const bool k0 = colok && ((unsigned)(pr0 + 0) <= 30u);
            const bool k1 = colok && ((unsigned)(pr0 + 1) <= 30u);
            const bool k2 = colok && ((unsigned)(pr0 + 2) <= 30u);
            const bool k3 = colok && ((unsigned)(pr0 + 3) <= 30u);
            a0 += k0 ? imgb[base + (pr0 + 0) * P + pc] : 0.f;
            a1 += k1 ? imgb[base + (pr0 + 1) * P + pc] : 0.f;
            a2 += k2 ? imgb[base + (pr0 + 2) * P + pc] : 0.f;
            a3 += k3 ? imgb[base + (pr0 + 3) * P + pc] : 0.f;
        }
        cur = nxt;
    }

    // store: 32 consecutive lanes per row segment -> full 128B line writes
    if (c < S) {
        const int rb = r0 + rowg * 4;
        const float accs[4] = {a0, a1, a2, a3};
        #pragma unroll
        for (int q = 0; q < 4; ++q) {
            const int r = rb + q;
            if (r < S) {
                out[(size_t)b * (S * S) + r * S + c] = accs[q];
            }
        }
    }
}

extern "C" void kernel_launch(void* const* d_in, const int* in_sizes, int n_in,
                              void* d_out, int out_size, void* d_ws, size_t ws_size,
                              hipStream_t stream)
{
    const float* img = (const float*)d_in[0];   // [B, E, P, P] fp32
    const int*   xyz = (const int*)d_in[1];     // [B, E, 3] int32
    float*       out = (float*)d_out;           // [B, 1, S, S] fp32

    int*      counts  = (int*)d_ws;
    unsigned* entries = (unsigned*)d_ws + NBINS;

    hipMemsetAsync(counts, 0, (size_t)NBINS * sizeof(int), stream);

    imgs4dto3d_bin_kernel<<<B, E, 0, stream>>>(xyz, counts, entries);

    dim3 grid(NTILES, B);                        // one block per (tile, batch)
    imgs4dto3d_gather_kernel<<<grid, THREADS, 0, stream>>>(img, counts, entries, out);
}